// Round 2
// baseline (1579.189 us; speedup 1.0000x reference)
//
#include <hip/hip_runtime.h>
#include <hip/hip_bf16.h>

// Elman RNN, round 6 (resubmit of round 5 — previous bench died to a container
// infra failure, no kernel signal).
// Diagnosis from round-4 counters: scan step = 1416 cyc, of which LDS pipe ~= 768
// (64 ds_read_b128) + 320 conflict cycles, MFMA only 620 -> scan is LDS-bound.
// Changes vs round 4:
//  - scan: 8 waves x 2 mtiles -> 4 waves x 4 mtiles. Every wave reads the FULL h
//    (B-frags depend only on lane,kt), so halving waves halves LDS read traffic
//    (64 -> 32 b128/step) at identical per-SIMD MFMA count.
//  - scan: lgkmcnt-only barrier (s_waitcnt lgkmcnt(0); s_barrier) so the xin
//    prefetch (vmcnt) spans the barrier; prefetch deepened to 2 steps.
//  - xin stored in MFMA-tile layout [(t*8+bx)*16+ht][lane] (uint2): phase-1 wave
//    writes and scan reads are contiguous 512-B bursts (was 8-B @ 512-B stride =
//    8x write amplification -> ~1 GB HBM writes; now 134 MB).
//  - phase-1 stages x through LDS per t (contiguous 512-B row segments) instead of
//    32-B per-lane strided reads.

#define BATCH 128
#define SEQ   2048
#define NIN   128
#define NH    256
#define NOUT  128

#define BTILE 16
#define NBLK  (BATCH / BTILE)      // 8
#define HPITCH 264                 // 256 + 8 pad (bf16)
#define XPITCH 136
#define TCHUNK 16
#define LOG2E 1.4426950408889634f

typedef __attribute__((ext_vector_type(8))) short short8;
typedef __attribute__((ext_vector_type(4))) float f32x4;

__device__ __forceinline__ ushort f2bf(float f) {
    union { float f; uint u; } v; v.f = f;
    uint r = v.u + 0x7fffu + ((v.u >> 16) & 1u);   // RNE
    return (ushort)(r >> 16);
}

__device__ __forceinline__ uint pk_bf16(float a, float b) {
    float2 p; p.x = a; p.y = b;
    __hip_bfloat162 h = __float22bfloat162_rn(p);
    union { __hip_bfloat162 h; uint u; } v; v.h = h; return v.u;
}

__device__ __forceinline__ short8 load_wfrag_s(const float* __restrict__ W, int ld,
                                               int row, int col, float scale) {
    const float4* p = (const float4*)(W + (size_t)row * ld + col);
    float4 a = p[0], b = p[1];
    union { short8 v; ushort u[8]; } r;
    r.u[0] = f2bf(a.x * scale); r.u[1] = f2bf(a.y * scale);
    r.u[2] = f2bf(a.z * scale); r.u[3] = f2bf(a.w * scale);
    r.u[4] = f2bf(b.x * scale); r.u[5] = f2bf(b.y * scale);
    r.u[6] = f2bf(b.z * scale); r.u[7] = f2bf(b.w * scale);
    return r.v;
}

__device__ __forceinline__ float bfhi2f(uint u) {
    union { uint u; float f; } v; v.u = u & 0xffff0000u; return v.f;
}
__device__ __forceinline__ float bflo2f(uint u) {
    union { uint u; float f; } v; v.u = u << 16; return v.f;
}

// ---------------- Phase 1: xin = log2e*(x.W_in^T + b_in), tile layout ----------------
// xin element index for (t, ht, lane): ((t*NBLK + bx)*16 + ht)*64 + lane  (uint2 each)
__global__ __launch_bounds__(256, 1)
void xin_gemm(const float* __restrict__ x,
              const float* __restrict__ W_in,
              const float* __restrict__ b_in,
              uint2* __restrict__ xin) {
    const int tid  = threadIdx.x;
    const int lane = tid & 63;
    const int wid  = tid >> 6;          // 0..3
    const int n15  = lane & 15;
    const int q    = lane >> 4;
    const int bblk = blockIdx.x * BTILE;
    const int t0   = blockIdx.y * TCHUNK;

    __shared__ __align__(16) ushort xlds[2][BTILE * XPITCH];  // 2 x 4352 B

    short8 win[4][4];
    float  bias[4][4];
    #pragma unroll
    for (int mt = 0; mt < 4; ++mt) {
        const int row = (wid * 4 + mt) * 16 + n15;
        #pragma unroll
        for (int kt = 0; kt < 4; ++kt)
            win[mt][kt] = load_wfrag_s(W_in, NIN, row, kt * 32 + q * 8, LOG2E);
        #pragma unroll
        for (int r = 0; r < 4; ++r)
            bias[mt][r] = LOG2E * b_in[(wid * 4 + mt) * 16 + q * 4 + r];
    }

    // cooperative x staging: thread -> (row = tid>>4, col = (tid&15)*8)
    const int xr = tid >> 4;
    const int xc = (tid & 15) * 8;
    const size_t xbase = ((size_t)(bblk + xr)) * SEQ * NIN + xc;
    {
        const float4* p = (const float4*)(x + xbase + (size_t)t0 * NIN);
        float4 a = p[0], b = p[1];
        union { uint4 u4; ushort s[8]; } px;
        px.s[0] = f2bf(a.x); px.s[1] = f2bf(a.y); px.s[2] = f2bf(a.z); px.s[3] = f2bf(a.w);
        px.s[4] = f2bf(b.x); px.s[5] = f2bf(b.y); px.s[6] = f2bf(b.z); px.s[7] = f2bf(b.w);
        *(uint4*)&xlds[0][xr * XPITCH + xc] = px.u4;
    }
    __syncthreads();

    #pragma unroll 1
    for (int tt = 0; tt < TCHUNK; ++tt) {
        const int t = t0 + tt;
        const int cur = tt & 1, nxt = cur ^ 1;

        float4 xp0{}, xp1{};
        if (tt + 1 < TCHUNK) {
            const float4* p = (const float4*)(x + xbase + (size_t)(t + 1) * NIN);
            xp0 = p[0]; xp1 = p[1];
        }

        short8 bx[4];
        #pragma unroll
        for (int kt = 0; kt < 4; ++kt)
            bx[kt] = *(const short8*)&xlds[cur][n15 * XPITCH + kt * 32 + q * 8];

        f32x4 acc[4];
        #pragma unroll
        for (int mt = 0; mt < 4; ++mt) {
            acc[mt][0] = bias[mt][0]; acc[mt][1] = bias[mt][1];
            acc[mt][2] = bias[mt][2]; acc[mt][3] = bias[mt][3];
        }
        #pragma unroll
        for (int kt = 0; kt < 4; ++kt)
            #pragma unroll
            for (int mt = 0; mt < 4; ++mt)
                acc[mt] = __builtin_amdgcn_mfma_f32_16x16x32_bf16(
                    win[mt][kt], bx[kt], acc[mt], 0, 0, 0);

        // coalesced tile store: per mt, wave writes 64 lanes x 8 B = 512 B contiguous
        const size_t tb = ((size_t)t * NBLK + blockIdx.x) * 16;
        #pragma unroll
        for (int mt = 0; mt < 4; ++mt) {
            uint2 w;
            w.x = pk_bf16(acc[mt][0], acc[mt][1]);
            w.y = pk_bf16(acc[mt][2], acc[mt][3]);
            xin[(tb + wid * 4 + mt) * 64 + lane] = w;
        }

        if (tt + 1 < TCHUNK) {
            union { uint4 u4; ushort s[8]; } px;
            px.s[0] = f2bf(xp0.x); px.s[1] = f2bf(xp0.y);
            px.s[2] = f2bf(xp0.z); px.s[3] = f2bf(xp0.w);
            px.s[4] = f2bf(xp1.x); px.s[5] = f2bf(xp1.y);
            px.s[6] = f2bf(xp1.z); px.s[7] = f2bf(xp1.w);
            *(uint4*)&xlds[nxt][xr * XPITCH + xc] = px.u4;
        }
        __syncthreads();
    }
}

// ---------------- Phase 2: sequential scan + output projection ----------------
// 4 waves x 4 m-tiles: halves LDS read traffic vs 8x2 (each wave reads full h).
__global__ __launch_bounds__(256, 1)
void elman_scan(const uint2* __restrict__ xin,
                const float* __restrict__ W_rec,
                const float* __restrict__ W_out,
                const float* __restrict__ b_out,
                float* __restrict__ out) {
    const int tid  = threadIdx.x;
    const int lane = tid & 63;
    const int wid  = tid >> 6;          // 0..3
    const int n15  = lane & 15;
    const int q    = lane >> 4;
    const int bblk = blockIdx.x * BTILE;

    __shared__ __align__(16) ushort hlds[2][BTILE * HPITCH];  // 2 x 8448 B

    // W_rec A-fragments (scaled by log2e) — 4 m-tiles per wave = 128 VGPRs
    short8 wrec[4][8];
    #pragma unroll
    for (int mt = 0; mt < 4; ++mt) {
        const int row = (wid * 4 + mt) * 16 + n15;
        #pragma unroll
        for (int kt = 0; kt < 8; ++kt)
            wrec[mt][kt] = load_wfrag_s(W_rec, NH, row, kt * 32 + q * 8, LOG2E);
    }

    // h0 = 0
    for (int i = tid; i < BTILE * HPITCH / 2; i += 256)
        ((uint*)hlds[0])[i] = 0u;

    // xin tile base for this (block, wave, lane); per-t stride = NBLK*16*64 uint2
    const size_t TSTRIDE = (size_t)NBLK * 16 * 64;  // 8192
    const uint2* xb0 = xin + (size_t)blockIdx.x * 16 * 64 + (size_t)(wid * 4) * 64 + lane;

    // 2-deep prefetch: xa holds even t, xb holds odd t
    uint2 xa[4], xb[4];
    #pragma unroll
    for (int mt = 0; mt < 4; ++mt) xa[mt] = xb0[mt * 64];             // t = 0
    #pragma unroll
    for (int mt = 0; mt < 4; ++mt) xb[mt] = xb0[TSTRIDE + mt * 64];   // t = 1

    __syncthreads();

    const int hbase = n15 * HPITCH;

    auto step = [&](int t, uint2 (&X)[4]) {
        const int cur = t & 1, nxt = cur ^ 1;

        // 1) issue h_t B-fragment reads (latency overlaps the VALU below)
        short8 bh[8];
        #pragma unroll
        for (int kt = 0; kt < 8; ++kt)
            bh[kt] = *(const short8*)&hlds[cur][hbase + kt * 32 + q * 8];

        // 2) acc init = scaled xin (bias folded)
        f32x4 acc[4];
        #pragma unroll
        for (int mt = 0; mt < 4; ++mt) {
            acc[mt][0] = bflo2f(X[mt].x);
            acc[mt][1] = bfhi2f(X[mt].x);
            acc[mt][2] = bflo2f(X[mt].y);
            acc[mt][3] = bfhi2f(X[mt].y);
        }

        // 3) prefetch xin_{t+2} into the just-consumed buffer (spans 2 barriers;
        //    barrier below waits lgkmcnt only, so these stay in flight)
        {
            const int tp = (t + 2 < SEQ) ? (t + 2) : (SEQ - 1);
            const uint2* p = xb0 + (size_t)tp * TSTRIDE;
            #pragma unroll
            for (int mt = 0; mt < 4; ++mt) X[mt] = p[mt * 64];
        }

        // 4) recurrent MFMAs: 4 independent chains x 8 deep
        #pragma unroll
        for (int kt = 0; kt < 8; ++kt)
            #pragma unroll
            for (int mt = 0; mt < 4; ++mt)
                acc[mt] = __builtin_amdgcn_mfma_f32_16x16x32_bf16(
                    wrec[mt][kt], bh[kt], acc[mt], 0, 0, 0);

        // 5) sigmoid(a) = rcp(1 + 2^(-z)), z = log2e*a already in acc
        #pragma unroll
        for (int mt = 0; mt < 4; ++mt) {
            float h0 = __builtin_amdgcn_rcpf(1.0f + __builtin_amdgcn_exp2f(-acc[mt][0]));
            float h1 = __builtin_amdgcn_rcpf(1.0f + __builtin_amdgcn_exp2f(-acc[mt][1]));
            float h2 = __builtin_amdgcn_rcpf(1.0f + __builtin_amdgcn_exp2f(-acc[mt][2]));
            float h3 = __builtin_amdgcn_rcpf(1.0f + __builtin_amdgcn_exp2f(-acc[mt][3]));
            uint2 w;
            w.x = pk_bf16(h0, h1);
            w.y = pk_bf16(h2, h3);
            *(uint2*)&hlds[nxt][hbase + (wid * 4 + mt) * 16 + q * 4] = w;
        }

        // lgkm-only barrier: LDS writes/reads drained, global prefetch NOT drained
        asm volatile("s_waitcnt lgkmcnt(0)" ::: "memory");
        __builtin_amdgcn_s_barrier();
    };

    #pragma unroll 1
    for (int t = 0; t < SEQ; t += 2) {
        step(t, xa);
        step(t + 1, xb);
    }

    // ---- output projection from hlds[0] (SEQ even): wave wid owns m-tiles 2wid..+1 ----
    short8 wout[2][8];
    float  bo[2][4];
    #pragma unroll
    for (int mo = 0; mo < 2; ++mo) {
        const int row = (wid * 2 + mo) * 16 + n15;
        #pragma unroll
        for (int kt = 0; kt < 8; ++kt)
            wout[mo][kt] = load_wfrag_s(W_out, NH, row, kt * 32 + q * 8, 1.0f);
        #pragma unroll
        for (int r = 0; r < 4; ++r)
            bo[mo][r] = b_out[(wid * 2 + mo) * 16 + q * 4 + r];
    }
    f32x4 oacc[2];
    #pragma unroll
    for (int mo = 0; mo < 2; ++mo) {
        oacc[mo][0] = bo[mo][0]; oacc[mo][1] = bo[mo][1];
        oacc[mo][2] = bo[mo][2]; oacc[mo][3] = bo[mo][3];
    }
    #pragma unroll
    for (int kt = 0; kt < 8; ++kt) {
        short8 bh = *(const short8*)&hlds[0][hbase + kt * 32 + q * 8];
        #pragma unroll
        for (int mo = 0; mo < 2; ++mo)
            oacc[mo] = __builtin_amdgcn_mfma_f32_16x16x32_bf16(wout[mo][kt], bh, oacc[mo], 0, 0, 0);
    }
    #pragma unroll
    for (int mo = 0; mo < 2; ++mo)
        #pragma unroll
        for (int r = 0; r < 4; ++r) {
            const int o = (wid * 2 + mo) * 16 + q * 4 + r;
            out[(size_t)(bblk + n15) * NOUT + o] = oacc[mo][r];
        }
}

// ---------------- Fallback (fully fused, round-2) if ws too small ----------------
__global__ __launch_bounds__(256, 1)
void elman_mfma(const float* __restrict__ x,
                const float* __restrict__ W_in,
                const float* __restrict__ b_in,
                const float* __restrict__ W_rec,
                const float* __restrict__ W_out,
                const float* __restrict__ b_out,
                float* __restrict__ out) {
    const int tid  = threadIdx.x;
    const int lane = tid & 63;
    const int wid  = tid >> 6;
    const int n15  = lane & 15;
    const int q    = lane >> 4;
    const int bblk = blockIdx.x * BTILE;

    __shared__ __align__(16) ushort hlds[2][BTILE * HPITCH];
    __shared__ __align__(16) ushort xlds[2][BTILE * XPITCH];

    short8 wrec[4][8];
    short8 win[4][4];
    float  bias[4][4];
    #pragma unroll
    for (int mt = 0; mt < 4; ++mt) {
        const int row = (wid * 4 + mt) * 16 + n15;
        #pragma unroll
        for (int kt = 0; kt < 8; ++kt)
            wrec[mt][kt] = load_wfrag_s(W_rec, NH, row, kt * 32 + q * 8, 1.0f);
        #pragma unroll
        for (int kt = 0; kt < 4; ++kt)
            win[mt][kt] = load_wfrag_s(W_in, NIN, row, kt * 32 + q * 8, 1.0f);
        #pragma unroll
        for (int r = 0; r < 4; ++r)
            bias[mt][r] = b_in[(wid * 4 + mt) * 16 + q * 4 + r];
    }

    for (int i = tid; i < BTILE * HPITCH / 2; i += 256)
        ((uint*)hlds[0])[i] = 0u;

    const int xr = tid >> 4;
    const int xc = (tid & 15) * 8;
    const size_t xbase = ((size_t)(bblk + xr)) * SEQ * NIN + xc;
    {
        const float4* p = (const float4*)(x + xbase);
        float4 a = p[0], b = p[1];
        union { uint4 u4; ushort s[8]; } px;
        px.s[0] = f2bf(a.x); px.s[1] = f2bf(a.y); px.s[2] = f2bf(a.z); px.s[3] = f2bf(a.w);
        px.s[4] = f2bf(b.x); px.s[5] = f2bf(b.y); px.s[6] = f2bf(b.z); px.s[7] = f2bf(b.w);
        *(uint4*)&xlds[0][xr * XPITCH + xc] = px.u4;
    }
    __syncthreads();

    #pragma unroll 1
    for (int t = 0; t < SEQ; ++t) {
        const int cur = t & 1, nxt = cur ^ 1;
        float4 xp0{}, xp1{};
        if (t + 1 < SEQ) {
            const float4* p = (const float4*)(x + xbase + (size_t)(t + 1) * NIN);
            xp0 = p[0]; xp1 = p[1];
        }
        short8 bx[4], bh[8];
        #pragma unroll
        for (int kt = 0; kt < 4; ++kt)
            bx[kt] = *(const short8*)&xlds[cur][n15 * XPITCH + kt * 32 + q * 8];
        #pragma unroll
        for (int kt = 0; kt < 8; ++kt)
            bh[kt] = *(const short8*)&hlds[cur][n15 * HPITCH + kt * 32 + q * 8];
        f32x4 acc[4];
        #pragma unroll
        for (int mt = 0; mt < 4; ++mt) {
            acc[mt][0] = bias[mt][0]; acc[mt][1] = bias[mt][1];
            acc[mt][2] = bias[mt][2]; acc[mt][3] = bias[mt][3];
        }
        #pragma unroll
        for (int kt = 0; kt < 4; ++kt)
            #pragma unroll
            for (int mt = 0; mt < 4; ++mt)
                acc[mt] = __builtin_amdgcn_mfma_f32_16x16x32_bf16(
                    win[mt][kt], bx[kt], acc[mt], 0, 0, 0);
        #pragma unroll
        for (int kt = 0; kt < 8; ++kt)
            #pragma unroll
            for (int mt = 0; mt < 4; ++mt)
                acc[mt] = __builtin_amdgcn_mfma_f32_16x16x32_bf16(
                    wrec[mt][kt], bh[kt], acc[mt], 0, 0, 0);
        #pragma unroll
        for (int mt = 0; mt < 4; ++mt) {
            float h0 = 1.0f / (1.0f + __expf(-acc[mt][0]));
            float h1 = 1.0f / (1.0f + __expf(-acc[mt][1]));
            float h2 = 1.0f / (1.0f + __expf(-acc[mt][2]));
            float h3 = 1.0f / (1.0f + __expf(-acc[mt][3]));
            uint2 w;
            w.x = pk_bf16(h0, h1);
            w.y = pk_bf16(h2, h3);
            *(uint2*)&hlds[nxt][n15 * HPITCH + (wid * 4 + mt) * 16 + q * 4] = w;
        }
        if (t + 1 < SEQ) {
            union { uint4 u4; ushort s[8]; } px;
            px.s[0] = f2bf(xp0.x); px.s[1] = f2bf(xp0.y);
            px.s[2] = f2bf(xp0.z); px.s[3] = f2bf(xp0.w);
            px.s[4] = f2bf(xp1.x); px.s[5] = f2bf(xp1.y);
            px.s[6] = f2bf(xp1.z); px.s[7] = f2bf(xp1.w);
            *(uint4*)&xlds[nxt][xr * XPITCH + xc] = px.u4;
        }
        __syncthreads();
    }

    short8 wout[2][8];
    float  bo[2][4];
    #pragma unroll
    for (int mo = 0; mo < 2; ++mo) {
        const int row = (wid * 2 + mo) * 16 + n15;
        #pragma unroll
        for (int kt = 0; kt < 8; ++kt)
            wout[mo][kt] = load_wfrag_s(W_out, NH, row, kt * 32 + q * 8, 1.0f);
        #pragma unroll
        for (int r = 0; r < 4; ++r)
            bo[mo][r] = b_out[(wid * 2 + mo) * 16 + q * 4 + r];
    }
    f32x4 oacc[2];
    #pragma unroll
    for (int mo = 0; mo < 2; ++mo) {
        oacc[mo][0] = bo[mo][0]; oacc[mo][1] = bo[mo][1];
        oacc[mo][2] = bo[mo][2]; oacc[mo][3] = bo[mo][3];
    }
    #pragma unroll
    for (int kt = 0; kt < 8; ++kt) {
        short8 bh = *(const short8*)&hlds[0][n15 * HPITCH + kt * 32 + q * 8];
        #pragma unroll
        for (int mo = 0; mo < 2; ++mo)
            oacc[mo] = __builtin_amdgcn_mfma_f32_16x16x32_bf16(
                wout[mo][kt], bh, oacc[mo], 0, 0, 0);
    }
    #pragma unroll
    for (int mo = 0; mo < 2; ++mo)
        #pragma unroll
        for (int r = 0; r < 4; ++r) {
            const int o = (wid * 2 + mo) * 16 + q * 4 + r;
            out[(size_t)(bblk + n15) * NOUT + o] = oacc[mo][r];
        }
}

extern "C" void kernel_launch(void* const* d_in, const int* in_sizes, int n_in,
                              void* d_out, int out_size, void* d_ws, size_t ws_size,
                              hipStream_t stream) {
    const float* x     = (const float*)d_in[0];
    const float* W_in  = (const float*)d_in[1];
    const float* b_in  = (const float*)d_in[2];
    const float* W_rec = (const float*)d_in[3];
    const float* W_out = (const float*)d_in[4];
    const float* b_out = (const float*)d_in[5];
    float* out = (float*)d_out;

    const size_t need = (size_t)SEQ * BATCH * NH * sizeof(ushort);  // 134 MB
    if (ws_size >= need) {
        uint2* xin = (uint2*)d_ws;
        dim3 g1(NBLK, SEQ / TCHUNK);   // 8 x 128 = 1024 blocks
        xin_gemm<<<g1, 256, 0, stream>>>(x, W_in, b_in, xin);
        elman_scan<<<NBLK, 256, 0, stream>>>(xin, W_rec, W_out, b_out, out);
    } else {
        elman_mfma<<<NBLK, 256, 0, stream>>>(x, W_in, b_in, W_rec, W_out, b_out, out);
    }
}

// Round 3
// 1364.579 us; speedup vs baseline: 1.1573x; 1.1573x over previous
//
#include <hip/hip_runtime.h>
#include <hip/hip_bf16.h>

// Elman RNN, round 7.
// Post-mortem r6: 4 waves x 4mt (1 wave/SIMD) lost MFMA/VALU co-scheduling -> scan
// regressed 1208->1360 despite halved LDS traffic. Fix: keep 8 waves (2/SIMD) and
// eliminate conflicts instead of traffic:
//  - h stored in LDS as interleaved C-tiles: uint2 at [slot*64 + c*4 + q'] where
//    slot = hidden>>4, c = batch col, q' = (hidden>>2)&3. Write (lane c,q') is a
//    bijective 8B scatter over 512B -> conflict-free. Read of B-frag kt for lane
//    (c,q) is ONE aligned ds_read_b128 at uint2-idx (2kt+(q>>1))*64 + 4c + 2(q&1):
//    rows 32kt+8q..+7, col c. 64 lanes cover a contiguous 1KB bijectively ->
//    conflict-free, no padding. (Verified by index algebra, samples in notes.)
//  - lgkm-only barrier + 2-deep xin prefetch kept from r6 (vmcnt floats across steps).
//  - phase 1: no LDS, no barriers. Each wave loads its own x B-frags (L1 absorbs
//    4x intra-block redundancy), 16 MFMA, tile-layout 512B coalesced stores.
//    TCHUNK=8, grid 8x256=2048 blocks -> full-machine TLP.

#define BATCH 128
#define SEQ   2048
#define NIN   128
#define NH    256
#define NOUT  128

#define BTILE 16
#define NBLK  (BATCH / BTILE)      // 8
#define HPITCH 264                 // (fallback kernel only)
#define XPITCH 136                 // (fallback kernel only)
#define TCHUNK 8                   // timesteps per phase-1 block
#define LOG2E 1.4426950408889634f

typedef __attribute__((ext_vector_type(8))) short short8;
typedef __attribute__((ext_vector_type(4))) float f32x4;

__device__ __forceinline__ ushort f2bf(float f) {
    union { float f; uint u; } v; v.f = f;
    uint r = v.u + 0x7fffu + ((v.u >> 16) & 1u);   // RNE
    return (ushort)(r >> 16);
}

__device__ __forceinline__ uint pk_bf16(float a, float b) {
    float2 p; p.x = a; p.y = b;
    __hip_bfloat162 h = __float22bfloat162_rn(p);
    union { __hip_bfloat162 h; uint u; } v; v.h = h; return v.u;
}

__device__ __forceinline__ short8 load_wfrag_s(const float* __restrict__ W, int ld,
                                               int row, int col, float scale) {
    const float4* p = (const float4*)(W + (size_t)row * ld + col);
    float4 a = p[0], b = p[1];
    union { short8 v; ushort u[8]; } r;
    r.u[0] = f2bf(a.x * scale); r.u[1] = f2bf(a.y * scale);
    r.u[2] = f2bf(a.z * scale); r.u[3] = f2bf(a.w * scale);
    r.u[4] = f2bf(b.x * scale); r.u[5] = f2bf(b.y * scale);
    r.u[6] = f2bf(b.z * scale); r.u[7] = f2bf(b.w * scale);
    return r.v;
}

__device__ __forceinline__ float bfhi2f(uint u) {
    union { uint u; float f; } v; v.u = u & 0xffff0000u; return v.f;
}
__device__ __forceinline__ float bflo2f(uint u) {
    union { uint u; float f; } v; v.u = u << 16; return v.f;
}

// ---------------- Phase 1: xin = log2e*(x.W_in^T + b_in), tile layout ----------------
// xin uint2 index for (t, slot=hidden>>4, lane): ((t*NBLK + bx)*16 + slot)*64 + lane
__global__ __launch_bounds__(256, 2)
void xin_gemm(const float* __restrict__ x,
              const float* __restrict__ W_in,
              const float* __restrict__ b_in,
              uint2* __restrict__ xin) {
    const int tid  = threadIdx.x;
    const int lane = tid & 63;
    const int wid  = tid >> 6;          // 0..3 -> m-tiles wid*4..wid*4+3
    const int n15  = lane & 15;
    const int q    = lane >> 4;
    const int bblk = blockIdx.x * BTILE;
    const int t0   = blockIdx.y * TCHUNK;

    short8 win[4][4];
    float  bias[4][4];
    #pragma unroll
    for (int mt = 0; mt < 4; ++mt) {
        const int row = (wid * 4 + mt) * 16 + n15;
        #pragma unroll
        for (int kt = 0; kt < 4; ++kt)
            win[mt][kt] = load_wfrag_s(W_in, NIN, row, kt * 32 + q * 8, LOG2E);
        #pragma unroll
        for (int r = 0; r < 4; ++r)
            bias[mt][r] = LOG2E * b_in[(wid * 4 + mt) * 16 + q * 4 + r];
    }

    // per-lane x B-frag source: row bblk+n15, cols kt*32 + q*8 .. +7
    const float* xrow = x + ((size_t)(bblk + n15) * SEQ + t0) * NIN + q * 8;

    #pragma unroll 1
    for (int tt = 0; tt < TCHUNK; ++tt) {
        const float* xp = xrow + (size_t)tt * NIN;
        short8 bx[4];
        #pragma unroll
        for (int kt = 0; kt < 4; ++kt) {
            const float4* p = (const float4*)(xp + kt * 32);
            float4 a = p[0], b = p[1];
            union { short8 v; ushort u[8]; } r;
            r.u[0] = f2bf(a.x); r.u[1] = f2bf(a.y); r.u[2] = f2bf(a.z); r.u[3] = f2bf(a.w);
            r.u[4] = f2bf(b.x); r.u[5] = f2bf(b.y); r.u[6] = f2bf(b.z); r.u[7] = f2bf(b.w);
            bx[kt] = r.v;
        }
        f32x4 acc[4];
        #pragma unroll
        for (int mt = 0; mt < 4; ++mt) {
            acc[mt][0] = bias[mt][0]; acc[mt][1] = bias[mt][1];
            acc[mt][2] = bias[mt][2]; acc[mt][3] = bias[mt][3];
        }
        #pragma unroll
        for (int kt = 0; kt < 4; ++kt)
            #pragma unroll
            for (int mt = 0; mt < 4; ++mt)
                acc[mt] = __builtin_amdgcn_mfma_f32_16x16x32_bf16(
                    win[mt][kt], bx[kt], acc[mt], 0, 0, 0);

        // coalesced tile store: per mt, wave writes 64 lanes x 8 B = 512 B contiguous
        const size_t tb = ((size_t)(t0 + tt) * NBLK + blockIdx.x) * 16;
        #pragma unroll
        for (int mt = 0; mt < 4; ++mt) {
            uint2 w;
            w.x = pk_bf16(acc[mt][0], acc[mt][1]);
            w.y = pk_bf16(acc[mt][2], acc[mt][3]);
            xin[(tb + wid * 4 + mt) * 64 + lane] = w;
        }
    }
}

// ---------------- Phase 2: sequential scan + output projection ----------------
// 8 waves x 2 m-tiles (2 waves/SIMD for MFMA/VALU co-scheduling), conflict-free
// interleaved h layout in LDS.
__global__ __launch_bounds__(512, 2)
void elman_scan(const uint2* __restrict__ xin,
                const float* __restrict__ W_rec,
                const float* __restrict__ W_out,
                const float* __restrict__ b_out,
                float* __restrict__ out) {
    const int tid  = threadIdx.x;
    const int lane = tid & 63;
    const int wid  = tid >> 6;          // 0..7 -> m-tiles wid*2, wid*2+1
    const int n15  = lane & 15;
    const int q    = lane >> 4;
    const int bblk = blockIdx.x * BTILE;

    // interleaved C-tile layout: uint2 at [slot*64 + c*4 + q']
    __shared__ __align__(16) uint2 hlds[2][16 * 64];   // 2 x 8 KB

    // W_rec A-fragments (scaled by log2e): 2 m-tiles x 8 kt = 64 VGPRs
    short8 wrec[2][8];
    #pragma unroll
    for (int mt = 0; mt < 2; ++mt) {
        const int row = (wid * 2 + mt) * 16 + n15;
        #pragma unroll
        for (int kt = 0; kt < 8; ++kt)
            wrec[mt][kt] = load_wfrag_s(W_rec, NH, row, kt * 32 + q * 8, LOG2E);
    }

    // h0 = 0
    for (int i = tid; i < 16 * 64; i += 512) {
        uint2 z; z.x = 0u; z.y = 0u;
        hlds[0][i] = z;
    }

    // xin tile base; per-t stride = NBLK*16*64 uint2
    const size_t TSTRIDE = (size_t)NBLK * 16 * 64;  // 8192
    const uint2* xb0 = xin + (size_t)blockIdx.x * 16 * 64 + (size_t)(wid * 2) * 64 + lane;

    uint2 xa[2], xb[2];
    #pragma unroll
    for (int mt = 0; mt < 2; ++mt) xa[mt] = xb0[mt * 64];             // t = 0
    #pragma unroll
    for (int mt = 0; mt < 2; ++mt) xb[mt] = xb0[TSTRIDE + mt * 64];   // t = 1

    __syncthreads();

    // B-frag read: rows 32kt+8q..+7, col n15 == one aligned b128 at this uint2 idx
    const int rbase = n15 * 4 + 2 * (q & 1);
    const int shalf = q >> 1;
    // write offset for this lane's C output (c*4 + q')
    const int woff  = n15 * 4 + q;

    auto step = [&](int t, uint2 (&X)[2]) {
        const int cur = t & 1, nxt = cur ^ 1;

        // 1) h_t B-fragments: 8 conflict-free ds_read_b128
        short8 bh[8];
        #pragma unroll
        for (int kt = 0; kt < 8; ++kt)
            bh[kt] = *(const short8*)&hlds[cur][(2 * kt + shalf) * 64 + rbase];

        // 2) acc init = scaled xin (bias folded)
        f32x4 acc[2];
        #pragma unroll
        for (int mt = 0; mt < 2; ++mt) {
            acc[mt][0] = bflo2f(X[mt].x);
            acc[mt][1] = bfhi2f(X[mt].x);
            acc[mt][2] = bflo2f(X[mt].y);
            acc[mt][3] = bfhi2f(X[mt].y);
        }

        // 3) prefetch xin_{t+2}; vmcnt floats across the lgkm-only barrier
        {
            const int tp = (t + 2 < SEQ) ? (t + 2) : (SEQ - 1);
            const uint2* p = xb0 + (size_t)tp * TSTRIDE;
            #pragma unroll
            for (int mt = 0; mt < 2; ++mt) X[mt] = p[mt * 64];
        }

        // 4) recurrent MFMAs: 2 independent chains x 8 deep
        #pragma unroll
        for (int kt = 0; kt < 8; ++kt)
            #pragma unroll
            for (int mt = 0; mt < 2; ++mt)
                acc[mt] = __builtin_amdgcn_mfma_f32_16x16x32_bf16(
                    wrec[mt][kt], bh[kt], acc[mt], 0, 0, 0);

        // 5) sigmoid(a) = rcp(1 + 2^(-z)), z = log2e*a already in acc; tile write
        #pragma unroll
        for (int mt = 0; mt < 2; ++mt) {
            float h0 = __builtin_amdgcn_rcpf(1.0f + __builtin_amdgcn_exp2f(-acc[mt][0]));
            float h1 = __builtin_amdgcn_rcpf(1.0f + __builtin_amdgcn_exp2f(-acc[mt][1]));
            float h2 = __builtin_amdgcn_rcpf(1.0f + __builtin_amdgcn_exp2f(-acc[mt][2]));
            float h3 = __builtin_amdgcn_rcpf(1.0f + __builtin_amdgcn_exp2f(-acc[mt][3]));
            uint2 w;
            w.x = pk_bf16(h0, h1);
            w.y = pk_bf16(h2, h3);
            hlds[nxt][(wid * 2 + mt) * 64 + woff] = w;
        }

        // lgkm-only barrier: LDS drained, global prefetch stays in flight
        asm volatile("s_waitcnt lgkmcnt(0)" ::: "memory");
        __builtin_amdgcn_s_barrier();
    };

    #pragma unroll 1
    for (int t = 0; t < SEQ; t += 2) {
        step(t, xa);
        step(t + 1, xb);
    }

    // ---- output projection from hlds[0] (SEQ even): wave wid owns m-tile wid ----
    short8 wout[8];
    float  bo[4];
    {
        const int row = wid * 16 + n15;
        #pragma unroll
        for (int kt = 0; kt < 8; ++kt)
            wout[kt] = load_wfrag_s(W_out, NH, row, kt * 32 + q * 8, 1.0f);
        #pragma unroll
        for (int r = 0; r < 4; ++r)
            bo[r] = b_out[wid * 16 + q * 4 + r];
    }
    f32x4 oacc;
    oacc[0] = bo[0]; oacc[1] = bo[1]; oacc[2] = bo[2]; oacc[3] = bo[3];
    #pragma unroll
    for (int kt = 0; kt < 8; ++kt) {
        short8 bh = *(const short8*)&hlds[0][(2 * kt + shalf) * 64 + rbase];
        oacc = __builtin_amdgcn_mfma_f32_16x16x32_bf16(wout[kt], bh, oacc, 0, 0, 0);
    }
    #pragma unroll
    for (int r = 0; r < 4; ++r) {
        const int o = wid * 16 + q * 4 + r;
        out[(size_t)(bblk + n15) * NOUT + o] = oacc[r];
    }
}

// ---------------- Fallback (fully fused, round-2) if ws too small ----------------
__global__ __launch_bounds__(256, 1)
void elman_mfma(const float* __restrict__ x,
                const float* __restrict__ W_in,
                const float* __restrict__ b_in,
                const float* __restrict__ W_rec,
                const float* __restrict__ W_out,
                const float* __restrict__ b_out,
                float* __restrict__ out) {
    const int tid  = threadIdx.x;
    const int lane = tid & 63;
    const int wid  = tid >> 6;
    const int n15  = lane & 15;
    const int q    = lane >> 4;
    const int bblk = blockIdx.x * BTILE;

    __shared__ __align__(16) ushort hlds[2][BTILE * HPITCH];
    __shared__ __align__(16) ushort xlds[2][BTILE * XPITCH];

    short8 wrec[4][8];
    short8 win[4][4];
    float  bias[4][4];
    #pragma unroll
    for (int mt = 0; mt < 4; ++mt) {
        const int row = (wid * 4 + mt) * 16 + n15;
        #pragma unroll
        for (int kt = 0; kt < 8; ++kt)
            wrec[mt][kt] = load_wfrag_s(W_rec, NH, row, kt * 32 + q * 8, 1.0f);
        #pragma unroll
        for (int kt = 0; kt < 4; ++kt)
            win[mt][kt] = load_wfrag_s(W_in, NIN, row, kt * 32 + q * 8, 1.0f);
        #pragma unroll
        for (int r = 0; r < 4; ++r)
            bias[mt][r] = b_in[(wid * 4 + mt) * 16 + q * 4 + r];
    }

    for (int i = tid; i < BTILE * HPITCH / 2; i += 256)
        ((uint*)hlds[0])[i] = 0u;

    const int xr = tid >> 4;
    const int xc = (tid & 15) * 8;
    const size_t xbase = ((size_t)(bblk + xr)) * SEQ * NIN + xc;
    {
        const float4* p = (const float4*)(x + xbase);
        float4 a = p[0], b = p[1];
        union { uint4 u4; ushort s[8]; } px;
        px.s[0] = f2bf(a.x); px.s[1] = f2bf(a.y); px.s[2] = f2bf(a.z); px.s[3] = f2bf(a.w);
        px.s[4] = f2bf(b.x); px.s[5] = f2bf(b.y); px.s[6] = f2bf(b.z); px.s[7] = f2bf(b.w);
        *(uint4*)&xlds[0][xr * XPITCH + xc] = px.u4;
    }
    __syncthreads();

    #pragma unroll 1
    for (int t = 0; t < SEQ; ++t) {
        const int cur = t & 1, nxt = cur ^ 1;
        float4 xp0{}, xp1{};
        if (t + 1 < SEQ) {
            const float4* p = (const float4*)(x + xbase + (size_t)(t + 1) * NIN);
            xp0 = p[0]; xp1 = p[1];
        }
        short8 bx[4], bh[8];
        #pragma unroll
        for (int kt = 0; kt < 4; ++kt)
            bx[kt] = *(const short8*)&xlds[cur][n15 * XPITCH + kt * 32 + q * 8];
        #pragma unroll
        for (int kt = 0; kt < 8; ++kt)
            bh[kt] = *(const short8*)&hlds[cur][n15 * HPITCH + kt * 32 + q * 8];
        f32x4 acc[4];
        #pragma unroll
        for (int mt = 0; mt < 4; ++mt) {
            acc[mt][0] = bias[mt][0]; acc[mt][1] = bias[mt][1];
            acc[mt][2] = bias[mt][2]; acc[mt][3] = bias[mt][3];
        }
        #pragma unroll
        for (int kt = 0; kt < 4; ++kt)
            #pragma unroll
            for (int mt = 0; mt < 4; ++mt)
                acc[mt] = __builtin_amdgcn_mfma_f32_16x16x32_bf16(
                    win[mt][kt], bx[kt], acc[mt], 0, 0, 0);
        #pragma unroll
        for (int kt = 0; kt < 8; ++kt)
            #pragma unroll
            for (int mt = 0; mt < 4; ++mt)
                acc[mt] = __builtin_amdgcn_mfma_f32_16x16x32_bf16(
                    wrec[mt][kt], bh[kt], acc[mt], 0, 0, 0);
        #pragma unroll
        for (int mt = 0; mt < 4; ++mt) {
            float h0 = 1.0f / (1.0f + __expf(-acc[mt][0]));
            float h1 = 1.0f / (1.0f + __expf(-acc[mt][1]));
            float h2 = 1.0f / (1.0f + __expf(-acc[mt][2]));
            float h3 = 1.0f / (1.0f + __expf(-acc[mt][3]));
            uint2 w;
            w.x = pk_bf16(h0, h1);
            w.y = pk_bf16(h2, h3);
            *(uint2*)&hlds[nxt][n15 * HPITCH + (wid * 4 + mt) * 16 + q * 4] = w;
        }
        if (t + 1 < SEQ) {
            union { uint4 u4; ushort s[8]; } px;
            px.s[0] = f2bf(xp0.x); px.s[1] = f2bf(xp0.y);
            px.s[2] = f2bf(xp0.z); px.s[3] = f2bf(xp0.w);
            px.s[4] = f2bf(xp1.x); px.s[5] = f2bf(xp1.y);
            px.s[6] = f2bf(xp1.z); px.s[7] = f2bf(xp1.w);
            *(uint4*)&xlds[nxt][xr * XPITCH + xc] = px.u4;
        }
        __syncthreads();
    }

    short8 wout[2][8];
    float  bo[2][4];
    #pragma unroll
    for (int mo = 0; mo < 2; ++mo) {
        const int row = (wid * 2 + mo) * 16 + n15;
        #pragma unroll
        for (int kt = 0; kt < 8; ++kt)
            wout[mo][kt] = load_wfrag_s(W_out, NH, row, kt * 32 + q * 8, 1.0f);
        #pragma unroll
        for (int r = 0; r < 4; ++r)
            bo[mo][r] = b_out[(wid * 2 + mo) * 16 + q * 4 + r];
    }
    f32x4 oacc[2];
    #pragma unroll
    for (int mo = 0; mo < 2; ++mo) {
        oacc[mo][0] = bo[mo][0]; oacc[mo][1] = bo[mo][1];
        oacc[mo][2] = bo[mo][2]; oacc[mo][3] = bo[mo][3];
    }
    #pragma unroll
    for (int kt = 0; kt < 8; ++kt) {
        short8 bh = *(const short8*)&hlds[0][n15 * HPITCH + kt * 32 + q * 8];
        #pragma unroll
        for (int mo = 0; mo < 2; ++mo)
            oacc[mo] = __builtin_amdgcn_mfma_f32_16x16x32_bf16(
                wout[mo][kt], bh, oacc[mo], 0, 0, 0);
    }
    #pragma unroll
    for (int mo = 0; mo < 2; ++mo)
        #pragma unroll
        for (int r = 0; r < 4; ++r) {
            const int o = (wid * 2 + mo) * 16 + q * 4 + r;
            out[(size_t)(bblk + n15) * NOUT + o] = oacc[mo][r];
        }
}

extern "C" void kernel_launch(void* const* d_in, const int* in_sizes, int n_in,
                              void* d_out, int out_size, void* d_ws, size_t ws_size,
                              hipStream_t stream) {
    const float* x     = (const float*)d_in[0];
    const float* W_in  = (const float*)d_in[1];
    const float* b_in  = (const float*)d_in[2];
    const float* W_rec = (const float*)d_in[3];
    const float* W_out = (const float*)d_in[4];
    const float* b_out = (const float*)d_in[5];
    float* out = (float*)d_out;

    const size_t need = (size_t)SEQ * BATCH * NH * sizeof(ushort);  // 134 MB
    if (ws_size >= need) {
        uint2* xin = (uint2*)d_ws;
        dim3 g1(NBLK, SEQ / TCHUNK);   // 8 x 256 = 2048 blocks
        xin_gemm<<<g1, 256, 0, stream>>>(x, W_in, b_in, xin);
        elman_scan<<<NBLK, 512, 0, stream>>>(xin, W_rec, W_out, b_out, out);
    } else {
        elman_mfma<<<NBLK, 256, 0, stream>>>(x, W_in, b_in, W_rec, W_out, b_out, out);
    }
}

// Round 5
// 1351.497 us; speedup vs baseline: 1.1685x; 1.0097x over previous
//
#include <hip/hip_runtime.h>
#include <hip/hip_bf16.h>

// Elman RNN, round 9.
// r8 post-mortem: NaN traced to hand-written v_cvt_pk_bf16_f32 inline asm (the
// only value-path change; guide m240 says don't hand-write it). r9 = r7 base +
// the two value-neutral r8 changes, packing via the proven builtin:
//  - __float22bfloat162_rn for ALL hot f32->bf16 packing (phase-1 x conversion
//    was 32 scalar f2bf ~ 96 VALU/lane/t; builtin pair-pack lets the compiler
//    emit packed cvt itself).
//  - s_setprio(1) around the scan MFMA cluster (T5; 2 waves/SIMD drift).
//  - 32-bit uniform xin indexing (saddr-friendly prefetch).
// Scan structure unchanged from r7 (passed, 1122 us): 8 waves x 2 m-tiles,
// conflict-free interleaved h C-tile layout, lgkm-only barrier, 2-deep prefetch.

#define BATCH 128
#define SEQ   2048
#define NIN   128
#define NH    256
#define NOUT  128

#define BTILE 16
#define NBLK  (BATCH / BTILE)      // 8
#define HPITCH 264                 // (fallback kernel only)
#define XPITCH 136                 // (fallback kernel only)
#define TCHUNK 8                   // timesteps per phase-1 block
#define LOG2E 1.4426950408889634f

typedef __attribute__((ext_vector_type(8))) short short8;
typedef __attribute__((ext_vector_type(4))) float f32x4;

__device__ __forceinline__ ushort f2bf(float f) {
    union { float f; uint u; } v; v.f = f;
    uint r = v.u + 0x7fffu + ((v.u >> 16) & 1u);   // RNE
    return (ushort)(r >> 16);
}

// packed f32->bf16 RNE via builtin (compiler lowers to packed cvt; m240: do not
// hand-write the asm)
__device__ __forceinline__ uint pk_bf16(float a, float b) {
    float2 p; p.x = a; p.y = b;
    __hip_bfloat162 h = __float22bfloat162_rn(p);
    union { __hip_bfloat162 h; uint u; } v; v.h = h; return v.u;
}

__device__ __forceinline__ short8 load_wfrag_s(const float* __restrict__ W, int ld,
                                               int row, int col, float scale) {
    const float4* p = (const float4*)(W + (size_t)row * ld + col);
    float4 a = p[0], b = p[1];
    union { short8 v; ushort u[8]; } r;
    r.u[0] = f2bf(a.x * scale); r.u[1] = f2bf(a.y * scale);
    r.u[2] = f2bf(a.z * scale); r.u[3] = f2bf(a.w * scale);
    r.u[4] = f2bf(b.x * scale); r.u[5] = f2bf(b.y * scale);
    r.u[6] = f2bf(b.z * scale); r.u[7] = f2bf(b.w * scale);
    return r.v;
}

__device__ __forceinline__ float bfhi2f(uint u) {
    union { uint u; float f; } v; v.u = u & 0xffff0000u; return v.f;
}
__device__ __forceinline__ float bflo2f(uint u) {
    union { uint u; float f; } v; v.u = u << 16; return v.f;
}

// ---------------- Phase 1: xin = log2e*(x.W_in^T + b_in), tile layout ----------------
// xin uint2 index for (t, slot=hidden>>4, lane): ((t*NBLK + bx)*16 + slot)*64 + lane
__global__ __launch_bounds__(256, 2)
void xin_gemm(const float* __restrict__ x,
              const float* __restrict__ W_in,
              const float* __restrict__ b_in,
              uint2* __restrict__ xin) {
    const int tid  = threadIdx.x;
    const int lane = tid & 63;
    const int wid  = tid >> 6;          // 0..3 -> m-tiles wid*4..wid*4+3
    const int n15  = lane & 15;
    const int q    = lane >> 4;
    const int bblk = blockIdx.x * BTILE;
    const int t0   = blockIdx.y * TCHUNK;

    short8 win[4][4];
    float  bias[4][4];
    #pragma unroll
    for (int mt = 0; mt < 4; ++mt) {
        const int row = (wid * 4 + mt) * 16 + n15;
        #pragma unroll
        for (int kt = 0; kt < 4; ++kt)
            win[mt][kt] = load_wfrag_s(W_in, NIN, row, kt * 32 + q * 8, LOG2E);
        #pragma unroll
        for (int r = 0; r < 4; ++r)
            bias[mt][r] = LOG2E * b_in[(wid * 4 + mt) * 16 + q * 4 + r];
    }

    // per-lane x B-frag source: row bblk+n15, cols kt*32 + q*8 .. +7
    const float* xrow = x + ((size_t)(bblk + n15) * SEQ + t0) * NIN + q * 8;

    #pragma unroll 1
    for (int tt = 0; tt < TCHUNK; ++tt) {
        const float* xp = xrow + (size_t)tt * NIN;
        short8 bx[4];
        #pragma unroll
        for (int kt = 0; kt < 4; ++kt) {
            const float4* p = (const float4*)(xp + kt * 32);
            float4 a = p[0], b = p[1];
            union { short8 v; uint u[4]; } r;
            r.u[0] = pk_bf16(a.x, a.y);
            r.u[1] = pk_bf16(a.z, a.w);
            r.u[2] = pk_bf16(b.x, b.y);
            r.u[3] = pk_bf16(b.z, b.w);
            bx[kt] = r.v;
        }
        f32x4 acc[4];
        #pragma unroll
        for (int mt = 0; mt < 4; ++mt) {
            acc[mt][0] = bias[mt][0]; acc[mt][1] = bias[mt][1];
            acc[mt][2] = bias[mt][2]; acc[mt][3] = bias[mt][3];
        }
        #pragma unroll
        for (int kt = 0; kt < 4; ++kt)
            #pragma unroll
            for (int mt = 0; mt < 4; ++mt)
                acc[mt] = __builtin_amdgcn_mfma_f32_16x16x32_bf16(
                    win[mt][kt], bx[kt], acc[mt], 0, 0, 0);

        // coalesced tile store: per mt, wave writes 64 lanes x 8 B = 512 B contiguous
        const uint tb = ((uint)(t0 + tt) * NBLK + blockIdx.x) * 16u;
        #pragma unroll
        for (int mt = 0; mt < 4; ++mt) {
            uint2 w;
            w.x = pk_bf16(acc[mt][0], acc[mt][1]);
            w.y = pk_bf16(acc[mt][2], acc[mt][3]);
            xin[(size_t)((tb + wid * 4 + mt) * 64u + lane)] = w;
        }
    }
}

// ---------------- Phase 2: sequential scan + output projection ----------------
// 8 waves x 2 m-tiles (2 waves/SIMD for MFMA/VALU co-scheduling), conflict-free
// interleaved h layout in LDS.
__global__ __launch_bounds__(512, 2)
void elman_scan(const uint2* __restrict__ xin,
                const float* __restrict__ W_rec,
                const float* __restrict__ W_out,
                const float* __restrict__ b_out,
                float* __restrict__ out) {
    const int tid  = threadIdx.x;
    const int lane = tid & 63;
    const int wid  = tid >> 6;          // 0..7 -> m-tiles wid*2, wid*2+1
    const int n15  = lane & 15;
    const int q    = lane >> 4;
    const int bblk = blockIdx.x * BTILE;

    // interleaved C-tile layout: uint2 at [slot*64 + c*4 + q']
    __shared__ __align__(16) uint2 hlds[2][16 * 64];   // 2 x 8 KB

    // W_rec A-fragments (scaled by log2e): 2 m-tiles x 8 kt = 64 VGPRs
    short8 wrec[2][8];
    #pragma unroll
    for (int mt = 0; mt < 2; ++mt) {
        const int row = (wid * 2 + mt) * 16 + n15;
        #pragma unroll
        for (int kt = 0; kt < 8; ++kt)
            wrec[mt][kt] = load_wfrag_s(W_rec, NH, row, kt * 32 + q * 8, LOG2E);
    }

    // h0 = 0
    for (int i = tid; i < 16 * 64; i += 512) {
        uint2 z; z.x = 0u; z.y = 0u;
        hlds[0][i] = z;
    }

    // xin element index (uint2 units), 32-bit math: per-t stride 8192
    const uint loff = (uint)blockIdx.x * 1024u + (uint)(wid * 2) * 64u + (uint)lane;

    uint2 xa[2], xb[2];
    #pragma unroll
    for (int mt = 0; mt < 2; ++mt) xa[mt] = xin[(size_t)(loff + mt * 64u)];           // t=0
    #pragma unroll
    for (int mt = 0; mt < 2; ++mt) xb[mt] = xin[(size_t)(8192u + loff + mt * 64u)];   // t=1

    __syncthreads();

    // B-frag read: rows 32kt+8q..+7, col n15 == one aligned b128 at this uint2 idx
    const int rbase = n15 * 4 + 2 * (q & 1);
    const int shalf = q >> 1;
    // write offset for this lane's C output (c*4 + q')
    const int woff  = n15 * 4 + q;

    auto step = [&](int t, uint2 (&X)[2]) {
        const int cur = t & 1, nxt = cur ^ 1;

        // 1) h_t B-fragments: 8 conflict-free ds_read_b128
        short8 bh[8];
        #pragma unroll
        for (int kt = 0; kt < 8; ++kt)
            bh[kt] = *(const short8*)&hlds[cur][(2 * kt + shalf) * 64 + rbase];

        // 2) acc init = scaled xin (bias folded)
        f32x4 acc[2];
        #pragma unroll
        for (int mt = 0; mt < 2; ++mt) {
            acc[mt][0] = bflo2f(X[mt].x);
            acc[mt][1] = bfhi2f(X[mt].x);
            acc[mt][2] = bflo2f(X[mt].y);
            acc[mt][3] = bfhi2f(X[mt].y);
        }

        // 3) prefetch xin_{t+2}; vmcnt floats across the lgkm-only barrier.
        //    uniform 32-bit offset -> scalar mul + cheap adds
        {
            const uint tp = (uint)((t + 2 < SEQ) ? (t + 2) : (SEQ - 1));
            const uint tb = tp * 8192u + loff;
            #pragma unroll
            for (int mt = 0; mt < 2; ++mt) X[mt] = xin[(size_t)(tb + mt * 64u)];
        }

        // 4) recurrent MFMAs: 2 independent chains x 8 deep; prioritized (T5)
        __builtin_amdgcn_s_setprio(1);
        #pragma unroll
        for (int kt = 0; kt < 8; ++kt)
            #pragma unroll
            for (int mt = 0; mt < 2; ++mt)
                acc[mt] = __builtin_amdgcn_mfma_f32_16x16x32_bf16(
                    wrec[mt][kt], bh[kt], acc[mt], 0, 0, 0);
        __builtin_amdgcn_s_setprio(0);

        // 5) sigmoid(a) = rcp(1 + 2^(-z)), z = log2e*a already in acc; tile write
        #pragma unroll
        for (int mt = 0; mt < 2; ++mt) {
            float h0 = __builtin_amdgcn_rcpf(1.0f + __builtin_amdgcn_exp2f(-acc[mt][0]));
            float h1 = __builtin_amdgcn_rcpf(1.0f + __builtin_amdgcn_exp2f(-acc[mt][1]));
            float h2 = __builtin_amdgcn_rcpf(1.0f + __builtin_amdgcn_exp2f(-acc[mt][2]));
            float h3 = __builtin_amdgcn_rcpf(1.0f + __builtin_amdgcn_exp2f(-acc[mt][3]));
            uint2 w;
            w.x = pk_bf16(h0, h1);
            w.y = pk_bf16(h2, h3);
            hlds[nxt][(wid * 2 + mt) * 64 + woff] = w;
        }

        // lgkm-only barrier: LDS drained, global prefetch stays in flight
        asm volatile("s_waitcnt lgkmcnt(0)" ::: "memory");
        __builtin_amdgcn_s_barrier();
    };

    #pragma unroll 1
    for (int t = 0; t < SEQ; t += 2) {
        step(t, xa);
        step(t + 1, xb);
    }

    // ---- output projection from hlds[0] (SEQ even): wave wid owns m-tile wid ----
    short8 wout[8];
    float  bo[4];
    {
        const int row = wid * 16 + n15;
        #pragma unroll
        for (int kt = 0; kt < 8; ++kt)
            wout[kt] = load_wfrag_s(W_out, NH, row, kt * 32 + q * 8, 1.0f);
        #pragma unroll
        for (int r = 0; r < 4; ++r)
            bo[r] = b_out[wid * 16 + q * 4 + r];
    }
    f32x4 oacc;
    oacc[0] = bo[0]; oacc[1] = bo[1]; oacc[2] = bo[2]; oacc[3] = bo[3];
    #pragma unroll
    for (int kt = 0; kt < 8; ++kt) {
        short8 bh = *(const short8*)&hlds[0][(2 * kt + shalf) * 64 + rbase];
        oacc = __builtin_amdgcn_mfma_f32_16x16x32_bf16(wout[kt], bh, oacc, 0, 0, 0);
    }
    #pragma unroll
    for (int r = 0; r < 4; ++r) {
        const int o = wid * 16 + q * 4 + r;
        out[(size_t)(bblk + n15) * NOUT + o] = oacc[r];
    }
}

// ---------------- Fallback (fully fused, round-2) if ws too small ----------------
__global__ __launch_bounds__(256, 1)
void elman_mfma(const float* __restrict__ x,
                const float* __restrict__ W_in,
                const float* __restrict__ b_in,
                const float* __restrict__ W_rec,
                const float* __restrict__ W_out,
                const float* __restrict__ b_out,
                float* __restrict__ out) {
    const int tid  = threadIdx.x;
    const int lane = tid & 63;
    const int wid  = tid >> 6;
    const int n15  = lane & 15;
    const int q    = lane >> 4;
    const int bblk = blockIdx.x * BTILE;

    __shared__ __align__(16) ushort hlds[2][BTILE * HPITCH];
    __shared__ __align__(16) ushort xlds[2][BTILE * XPITCH];

    short8 wrec[4][8];
    short8 win[4][4];
    float  bias[4][4];
    #pragma unroll
    for (int mt = 0; mt < 4; ++mt) {
        const int row = (wid * 4 + mt) * 16 + n15;
        #pragma unroll
        for (int kt = 0; kt < 8; ++kt)
            wrec[mt][kt] = load_wfrag_s(W_rec, NH, row, kt * 32 + q * 8, 1.0f);
        #pragma unroll
        for (int kt = 0; kt < 4; ++kt)
            win[mt][kt] = load_wfrag_s(W_in, NIN, row, kt * 32 + q * 8, 1.0f);
        #pragma unroll
        for (int r = 0; r < 4; ++r)
            bias[mt][r] = b_in[(wid * 4 + mt) * 16 + q * 4 + r];
    }

    for (int i = tid; i < BTILE * HPITCH / 2; i += 256)
        ((uint*)hlds[0])[i] = 0u;

    const int xr = tid >> 4;
    const int xc = (tid & 15) * 8;
    const size_t xbase = ((size_t)(bblk + xr)) * SEQ * NIN + xc;
    {
        const float4* p = (const float4*)(x + xbase);
        float4 a = p[0], b = p[1];
        union { uint4 u4; ushort s[8]; } px;
        px.s[0] = f2bf(a.x); px.s[1] = f2bf(a.y); px.s[2] = f2bf(a.z); px.s[3] = f2bf(a.w);
        px.s[4] = f2bf(b.x); px.s[5] = f2bf(b.y); px.s[6] = f2bf(b.z); px.s[7] = f2bf(b.w);
        *(uint4*)&xlds[0][xr * XPITCH + xc] = px.u4;
    }
    __syncthreads();

    #pragma unroll 1
    for (int t = 0; t < SEQ; ++t) {
        const int cur = t & 1, nxt = cur ^ 1;
        float4 xp0{}, xp1{};
        if (t + 1 < SEQ) {
            const float4* p = (const float4*)(x + xbase + (size_t)(t + 1) * NIN);
            xp0 = p[0]; xp1 = p[1];
        }
        short8 bx[4], bh[8];
        #pragma unroll
        for (int kt = 0; kt < 4; ++kt)
            bx[kt] = *(const short8*)&xlds[cur][n15 * XPITCH + kt * 32 + q * 8];
        #pragma unroll
        for (int kt = 0; kt < 8; ++kt)
            bh[kt] = *(const short8*)&hlds[cur][n15 * HPITCH + kt * 32 + q * 8];
        f32x4 acc[4];
        #pragma unroll
        for (int mt = 0; mt < 4; ++mt) {
            acc[mt][0] = bias[mt][0]; acc[mt][1] = bias[mt][1];
            acc[mt][2] = bias[mt][2]; acc[mt][3] = bias[mt][3];
        }
        #pragma unroll
        for (int kt = 0; kt < 4; ++kt)
            #pragma unroll
            for (int mt = 0; mt < 4; ++mt)
                acc[mt] = __builtin_amdgcn_mfma_f32_16x16x32_bf16(
                    win[mt][kt], bx[kt], acc[mt], 0, 0, 0);
        #pragma unroll
        for (int kt = 0; kt < 8; ++kt)
            #pragma unroll
            for (int mt = 0; mt < 4; ++mt)
                acc[mt] = __builtin_amdgcn_mfma_f32_16x16x32_bf16(
                    wrec[mt][kt], bh[kt], acc[mt], 0, 0, 0);
        #pragma unroll
        for (int mt = 0; mt < 4; ++mt) {
            float h0 = 1.0f / (1.0f + __expf(-acc[mt][0]));
            float h1 = 1.0f / (1.0f + __expf(-acc[mt][1]));
            float h2 = 1.0f / (1.0f + __expf(-acc[mt][2]));
            float h3 = 1.0f / (1.0f + __expf(-acc[mt][3]));
            uint2 w;
            w.x = pk_bf16(h0, h1);
            w.y = pk_bf16(h2, h3);
            *(uint2*)&hlds[nxt][n15 * HPITCH + (wid * 4 + mt) * 16 + q * 4] = w;
        }
        if (t + 1 < SEQ) {
            union { uint4 u4; ushort s[8]; } px;
            px.s[0] = f2bf(xp0.x); px.s[1] = f2bf(xp0.y);
            px.s[2] = f2bf(xp0.z); px.s[3] = f2bf(xp0.w);
            px.s[4] = f2bf(xp1.x); px.s[5] = f2bf(xp1.y);
            px.s[6] = f2bf(xp1.z); px.s[7] = f2bf(xp1.w);
            *(uint4*)&xlds[nxt][xr * XPITCH + xc] = px.u4;
        }
        __syncthreads();
    }

    short8 wout[2][8];
    float  bo[2][4];
    #pragma unroll
    for (int mo = 0; mo < 2; ++mo) {
        const int row = (wid * 2 + mo) * 16 + n15;
        #pragma unroll
        for (int kt = 0; kt < 8; ++kt)
            wout[mo][kt] = load_wfrag_s(W_out, NH, row, kt * 32 + q * 8, 1.0f);
        #pragma unroll
        for (int r = 0; r < 4; ++r)
            bo[mo][r] = b_out[(wid * 2 + mo) * 16 + q * 4 + r];
    }
    f32x4 oacc[2];
    #pragma unroll
    for (int mo = 0; mo < 2; ++mo) {
        oacc[mo][0] = bo[mo][0]; oacc[mo][1] = bo[mo][1];
        oacc[mo][2] = bo[mo][2]; oacc[mo][3] = bo[mo][3];
    }
    #pragma unroll
    for (int kt = 0; kt < 8; ++kt) {
        short8 bh = *(const short8*)&hlds[0][n15 * HPITCH + kt * 32 + q * 8];
        #pragma unroll
        for (int mo = 0; mo < 2; ++mo)
            oacc[mo] = __builtin_amdgcn_mfma_f32_16x16x32_bf16(
                wout[mo][kt], bh, oacc[mo], 0, 0, 0);
    }
    #pragma unroll
    for (int mo = 0; mo < 2; ++mo)
        #pragma unroll
        for (int r = 0; r < 4; ++r) {
            const int o = (wid * 2 + mo) * 16 + q * 4 + r;
            out[(size_t)(bblk + n15) * NOUT + o] = oacc[mo][r];
        }
}

extern "C" void kernel_launch(void* const* d_in, const int* in_sizes, int n_in,
                              void* d_out, int out_size, void* d_ws, size_t ws_size,
                              hipStream_t stream) {
    const float* x     = (const float*)d_in[0];
    const float* W_in  = (const float*)d_in[1];
    const float* b_in  = (const float*)d_in[2];
    const float* W_rec = (const float*)d_in[3];
    const float* W_out = (const float*)d_in[4];
    const float* b_out = (const float*)d_in[5];
    float* out = (float*)d_out;

    const size_t need = (size_t)SEQ * BATCH * NH * sizeof(ushort);  // 134 MB
    if (ws_size >= need) {
        uint2* xin = (uint2*)d_ws;
        dim3 g1(NBLK, SEQ / TCHUNK);   // 8 x 256 = 2048 blocks
        xin_gemm<<<g1, 256, 0, stream>>>(x, W_in, b_in, xin);
        elman_scan<<<NBLK, 512, 0, stream>>>(xin, W_rec, W_out, b_out, out);
    } else {
        elman_mfma<<<NBLK, 256, 0, stream>>>(x, W_in, b_in, W_rec, W_out, b_out, out);
    }
}